// Round 11
// baseline (121.304 us; speedup 1.0000x reference)
//
#include <hip/hip_runtime.h>
#include <hip/hip_fp16.h>

// gap_2370821948148 — circle-loss scalar reduction. B=4096, K=64, N=65.
// r28: FINALIZE PIN+FENCE. r27's -7.2us proved the old finalize was
// load-sink serialized (~32 latency periods, same pathology as r21's
// fused VGPR=44). r28 finishes the cure: 1024 thr, 2 float4/thread,
// all loads issued -> "+v" pin -> memory fence -> accumulate = ONE
// latency period. Fused kernel byte-identical to r25/r27 (proven best).
//
// SESSION LEDGER (why this shape):
//   - f32 inputs / bf16 scalar output (r5 inf proved f32; r2/r6 exact-0.0
//     proved the u16 bf16 readback).
//   - ~90us harness-fixed: 276MB ws 0xAA re-poison (~42us fill) + input
//     restores + graph gaps. Controllable = kernels (~31us).
//   - r18 WIN (131.9): f32 tile + VGPR cap up + fdot2.
//   - r19 REGRESS (139.2): coop staging + barrier (17KB vmcnt drain).
//   - r20 WIN (130.4): zero-LDS, lane-local row gathers + readlane.
//   - r21 REGRESS (132.4): VGPR_Count=44 proof of compiler LOAD-SINKING.
//   - r22 WIN (129.1): "+v" pin + asm memory fence -> one latency period.
//   - r23 REGRESS (134.8): tiny barriers cost ~5us on fused path. NEVER.
//   - r24 WIN (128.4): 2048 blocks x 4 indep waves (CP theory mostly dead).
//   - r25 WIN (127.9): minwaves 3->5 (VGPR cap 102).
//   - r26 REGRESS (129.0): burst-before-preamble. Issue order r25 kept.
//   - r27 WIN (120.7, BEST): finalize float4/512thr — old finalize was
//     ~9us of load-sink serial latency. Same disease, same cure.
//   - SPILL TRAP (r11/r12/r14/r15): fired at minwaves>=7 WITH barrier;
//     or ch+vcol co-live. Fused: branches disjoint, no barrier, mw=5.
//   - DO-NOT-USE: single-kernel last-block finalize (r3/r4 silent out==0).
//
// Structure: 2 batches/block, 256 thr = 4 independent waves.
//   wv&1==0: loss1. Lane l = row l: 16 float4 + slack, pinned+fenced;
//            anchors j via v_readlane. hc[32] packed-f16 hinge.
//   wv&1==1: loss2. Lane l = col l: 64 coalesced dwords + slack, pinned+
//            fenced; points r via v_readlane. Same hinge.
//   Partials to ws (plain stores, poison-proof); finalize (1024 thr,
//   pinned loads, 16-wave LDS reduce) writes 4-byte dual-encoded bf16.

#define R2_POS 0.36f     // 0.6^2
#define R2_NEG 1.44f     // (2*0.6)^2
#define GAMMA_C 0.5f
#define NBATCH 4096
#define NPART (NBATCH * 2)
#define HCNEG -1024.0f   // hinge filler: ps+gamma+HCNEG << 0 in f16 range

typedef _Float16 hf2 __attribute__((ext_vector_type(2)));
typedef float f4v __attribute__((ext_vector_type(4)));

__device__ __forceinline__ int maskbit(const void* p, int i, int mode) {
    if (mode == 0) return ((const unsigned*)p)[i] != 0u;          // 4B elems
    if (mode == 1) return ((const unsigned short*)p)[i] != 0;     // 2B elems
    return ((const unsigned char*)p)[i] != 0;                     // u8/bool
}

__device__ __forceinline__ float sload(float v) {   // pin uniform to SGPR
    return __uint_as_float(__builtin_amdgcn_readfirstlane(__float_as_uint(v)));
}

__device__ __forceinline__ float rlane(float v, int i) {  // wave broadcast
    return __uint_as_float(__builtin_amdgcn_readlane(__float_as_uint(v), i));
}

__global__ __launch_bounds__(256, 5)
void fused_kernel(const float* __restrict__ posp,
                  const float* __restrict__ ancp,
                  const void* __restrict__ pmp,
                  const void* __restrict__ amp,
                  const float* __restrict__ msp,
                  const float* __restrict__ xfp,
                  float* __restrict__ partials) {
    const int tid = threadIdx.x;
    const int wv = tid >> 6;             // wave 0..3 (independent)
    const int l = tid & 63;              // lane
    const int b = blockIdx.x * 2 + (wv >> 1);   // batch for this wave
    const int w = wv & 1;                // 0 = rows (loss1), 1 = cols (loss2)

    // ---- mask element-width detection (uniform, cached) ----
    unsigned mw0 = ((const unsigned*)pmp)[l];
    bool okw = (mw0 == 0u) || (mw0 == 1u) || (mw0 == 0x3F800000u);
    unsigned hh0 = mw0 & 0xFFFFu, hh1 = mw0 >> 16;
    bool okh = (hh0 == 0u || hh0 == 0x3F80u) && (hh1 == 0u || hh1 == 0x3F80u);
    int mmode = (__ballot(okw) == ~0ULL) ? 0 : ((__ballot(okh) == ~0ULL) ? 1 : 2);

    // ---- transform, pinned to SGPRs ----
    float T[12];
#pragma unroll
    for (int e = 0; e < 3; ++e)
#pragma unroll
        for (int d = 0; d < 4; ++d) T[e * 4 + d] = sload(xfp[e * 4 + d]);

    // ---- own points: lane l = point l of batch b ----
    const int pb = (b * 64 + l) * 3;
    const float px = posp[pb], py = posp[pb + 1], pz = posp[pb + 2];
    const float r0 = ancp[pb], r1 = ancp[pb + 1], r2 = ancp[pb + 2];
    const float ax = T[0] * r0 + T[1] * r1 + T[2]  * r2 + T[3];
    const float ay = T[4] * r0 + T[5] * r1 + T[6]  * r2 + T[7];
    const float az = T[8] * r0 + T[9] * r1 + T[10] * r2 + T[11];

    // ---- masks -> per-wave ballots (SGPR pairs) ----
    const int mi = b * 64 + l;
    const unsigned long long pmM = __ballot(maskbit(pmp, mi, mmode) != 0);
    const unsigned long long amM = __ballot(maskbit(amp, mi, mmode) != 0);

    float psum = 0.f; int pcnt = 0; float slack;
    hf2 hc[32];                          // packed hinge candidates (32 VGPR)

    if (w == 0) {
        // ===== loss1: lane l = row l; 65 contiguous floats, lane-local ====
        const float* rowp = msp + (size_t)b * 4225 + l * 65;
        f4v ch[16];
#pragma unroll
        for (int c = 0; c < 16; ++c)
            __builtin_memcpy(&ch[c], rowp + 4 * c, 16);   // global_load_dwordx4
        slack = rowp[64];
        // ---- pin + fence: loads may NOT sink below this point ----
#pragma unroll
        for (int c = 0; c < 16; ++c) asm volatile("" : "+v"(ch[c]));
        asm volatile("" : "+v"(slack));
        asm volatile("" ::: "memory");

        const bool pmL = (pmM >> l) & 1ULL;
#pragma unroll
        for (int jj = 0; jj < 32; ++jj) {
            float h0, h1;
#pragma unroll
            for (int s = 0; s < 2; ++s) {
                const int j = 2 * jj + s;
                float v = ch[j >> 2][j & 3];           // register
                float bx = rlane(ax, j);               // anchor j broadcast
                float by = rlane(ay, j);
                float bz = rlane(az, j);
                float dx = px - bx, dy = py - by, dz = pz - bz;
                float d2 = dx * dx + dy * dy + dz * dz;
                bool pos = pmL && ((amM >> j) & 1ULL) && (d2 < R2_POS);
                psum -= pos ? v : 0.f;
                pcnt += pos ? 1 : 0;
                float hcv = (d2 > R2_NEG) ? v : HCNEG; // gt_neg UNMASKED
                if (s == 0) h0 = hcv; else h1 = hcv;
            }
            hf2 h; h[0] = (_Float16)h0; h[1] = (_Float16)h1;
            hc[jj] = h;
        }
    } else {
        // ===== loss2: lane l = col l; 64 coalesced dwords + slack, pinned =
        const float* mcol = msp + (size_t)b * 4225 + l;
        float vcol[64];
#pragma unroll
        for (int r = 0; r < 64; ++r) vcol[r] = mcol[r * 65];
        slack = mcol[64 * 65];
        // ---- pin + fence: loads may NOT sink below this point ----
#pragma unroll
        for (int r = 0; r < 64; ++r) asm volatile("" : "+v"(vcol[r]));
        asm volatile("" : "+v"(slack));
        asm volatile("" ::: "memory");

        const bool amL = (amM >> l) & 1ULL;
#pragma unroll
        for (int jj = 0; jj < 32; ++jj) {
            float h0, h1;
#pragma unroll
            for (int s = 0; s < 2; ++s) {
                const int r = 2 * jj + s;
                float v = vcol[r];                     // register
                float qx = rlane(px, r);               // point r broadcast
                float qy = rlane(py, r);
                float qz = rlane(pz, r);
                float dx = qx - ax, dy = qy - ay, dz = qz - az;
                float d2 = dx * dx + dy * dy + dz * dz;
                bool pos = ((pmM >> r) & 1ULL) && amL && (d2 < R2_POS);
                psum -= pos ? v : 0.f;
                pcnt += pos ? 1 : 0;
                float hcv = (d2 > R2_NEG) ? v : HCNEG;
                if (s == 0) h0 = hcv; else h1 = hcv;
            }
            hf2 h; h[0] = (_Float16)h0; h[1] = (_Float16)h1;
            hc[jj] = h;
        }
    }

    const float ps = pcnt ? psum / (float)pcnt : -slack;

    // ---- packed branch-free hinge: max(hc + (ps+gamma), 0), f32 accum ----
    const _Float16 ch16 = (_Float16)(ps + GAMMA_C);
    const hf2 C2 = {ch16, ch16};
    const hf2 Z = {(_Float16)0.f, (_Float16)0.f};
    float hv = 0.f;
#if __has_builtin(__builtin_amdgcn_fdot2)
    const hf2 ONE2 = {(_Float16)1.f, (_Float16)1.f};
#pragma unroll
    for (int k = 0; k < 32; ++k) {
        hf2 x = hc[k] + C2;                  // v_pk_add_f16
        x = __builtin_elementwise_max(x, Z); // v_pk_max_f16
        hv = __builtin_amdgcn_fdot2(x, ONE2, hv, false); // v_dot2_f32_f16
    }
#else
#pragma unroll
    for (int k = 0; k < 32; ++k) {
        hf2 x = hc[k] + C2;                  // v_pk_add_f16
        x = __builtin_elementwise_max(x, Z); // v_pk_max_f16
        hv += (float)x[0] + (float)x[1];
    }
#endif
    if (pcnt) hv += fmaxf(ps + slack + GAMMA_C, 0.f);
    float result = __logf(hv + 1.f);

    // ---- one butterfly per wave, lane0 stores partial ----
#pragma unroll
    for (int off = 1; off < 64; off <<= 1)
        result += __shfl_xor(result, off, 64);
    if (l == 0) partials[b * 2 + w] = result;          // plain store, no init
}

// Finalize: 1024 thr, 2 float4/thread, PINNED+FENCED (one latency period),
// 16-wave LDS reduce. Barrier OK here (off the fused value path).
// 4-byte dual-encoded write: low u16 = exact bf16 bits.
__global__ __launch_bounds__(1024)
void finalize_kernel(const float* __restrict__ partials,
                     unsigned* __restrict__ out) {
    __shared__ float red[16];
    const int tid = threadIdx.x;
    // NPART floats = 2048 float4s; 1024 threads -> 2 float4 each.
    const f4v* p4 = (const f4v*)partials;
    f4v a = p4[tid];
    f4v c = p4[tid + 1024];
    asm volatile("" : "+v"(a));
    asm volatile("" : "+v"(c));
    asm volatile("" ::: "memory");
    float s = (a[0] + a[1]) + (a[2] + a[3]) + (c[0] + c[1]) + (c[2] + c[3]);
#pragma unroll
    for (int off = 1; off < 64; off <<= 1) s += __shfl_xor(s, off, 64);
    if ((tid & 63) == 0) red[tid >> 6] = s;
    __syncthreads();
    if (tid == 0) {
        float tot = 0.f;
#pragma unroll
        for (int i = 0; i < 16; ++i) tot += red[i];
        float loss = tot * (1.0f / (2.0f * NBATCH * 64.0f));
        unsigned bits = __float_as_uint(loss);
        unsigned h = (bits + 0x7FFFu + ((bits >> 16) & 1u)) >> 16;  // rne bf16
        out[0] = (h << 16) | h;
    }
}

extern "C" void kernel_launch(void* const* d_in, const int* in_sizes, int n_in,
                              void* d_out, int out_size, void* d_ws, size_t ws_size,
                              hipStream_t stream) {
    (void)in_sizes; (void)n_in; (void)out_size; (void)ws_size;
    const float* posp = (const float*)d_in[0];
    const float* ancp = (const float*)d_in[1];
    const void* pmp = d_in[2];
    const void* amp = d_in[3];
    const float* msp = (const float*)d_in[4];
    const float* xfp = (const float*)d_in[5];

    // ws[0..NPART): per-wave partials, fully overwritten every call.
    // 2048 blocks x 4 independent waves.
    fused_kernel<<<NBATCH / 2, 256, 0, stream>>>(posp, ancp, pmp, amp, msp,
                                                 xfp, (float*)d_ws);
    finalize_kernel<<<1, 1024, 0, stream>>>((const float*)d_ws,
                                            (unsigned*)d_out);
}

// Round 12
// 120.819 us; speedup vs baseline: 1.0040x; 1.0040x over previous
//
#include <hip/hip_runtime.h>
#include <hip/hip_fp16.h>

// gap_2370821948148 — circle-loss scalar reduction. B=4096, K=64, N=65.
// r29 = r27 byte-identical LOCK-IN (session best, 120.7us). r28's extra
// finalize pin+fence was neutral/slight-regress (+0.6): with 16 waves in
// one block, TLP already hides the 2048-load latency — the r22 pin cure
// only pays on WAVE-SERIAL paths. Reverted.
//
// SESSION LEDGER (final):
//   - f32 inputs / bf16 scalar output (r5 inf proved f32; r2/r6 exact-0.0
//     proved the u16 bf16 readback).
//   - ~90us harness-fixed: 276MB ws 0xAA re-poison (~42us fill @82% HBM) +
//     input restores + graph gaps. Controllable = kernels (~31us).
//   - r18 WIN (131.9): f32 tile + VGPR cap up + fdot2.
//   - r19 REGRESS (139.2): coop staging + barrier (17KB vmcnt drain).
//   - r20 WIN (130.4): zero-LDS, lane-local row gathers + readlane.
//   - r21 REGRESS (132.4): VGPR_Count=44 proof of compiler LOAD-SINKING.
//   - r22 WIN (129.1): "+v" pin + asm memory fence -> one latency period.
//   - r23 REGRESS (134.8): tiny barriers cost ~5us on fused path. NEVER.
//   - r24 WIN (128.4): 2048 blocks x 4 indep waves (CP theory mostly dead).
//   - r25 WIN (127.9): minwaves 3->5 (VGPR cap 102).
//   - r26 REGRESS (129.0): burst-before-preamble. Issue order r25 kept.
//   - r27 WIN (120.7, BEST): finalize float4/512thr — old finalize was
//     ~9us load-sink serial latency. Same disease as r21, same cure.
//   - r28 NEUTRAL (121.3): finalize pin+fence — TLP already covers it.
//   - Fused residual ~30us: HBM 14%, VALU 30%, conflicts 0, occ 40% —
//     latency-structure floor; 16 structural variants bracket it.
//   - SPILL TRAP: big reg arrays live across barrier, or ch+vcol co-live.
//   - DO-NOT-USE: single-kernel last-block finalize (r3/r4 silent out==0).
//
// Structure: 2 batches/block, 256 thr = 4 independent waves.
//   wv&1==0: loss1. Lane l = row l: 16 float4 + slack, pinned+fenced;
//            anchors j via v_readlane. hc[32] packed-f16 hinge.
//   wv&1==1: loss2. Lane l = col l: 64 coalesced dwords + slack, pinned+
//            fenced; points r via v_readlane. Same hinge.
//   Partials to ws (plain stores, poison-proof), separate unconditional
//   finalize (512 thr, float4) writes 4-byte dual-encoded bf16.

#define R2_POS 0.36f     // 0.6^2
#define R2_NEG 1.44f     // (2*0.6)^2
#define GAMMA_C 0.5f
#define NBATCH 4096
#define NPART (NBATCH * 2)
#define HCNEG -1024.0f   // hinge filler: ps+gamma+HCNEG << 0 in f16 range

typedef _Float16 hf2 __attribute__((ext_vector_type(2)));
typedef float f4v __attribute__((ext_vector_type(4)));

__device__ __forceinline__ int maskbit(const void* p, int i, int mode) {
    if (mode == 0) return ((const unsigned*)p)[i] != 0u;          // 4B elems
    if (mode == 1) return ((const unsigned short*)p)[i] != 0;     // 2B elems
    return ((const unsigned char*)p)[i] != 0;                     // u8/bool
}

__device__ __forceinline__ float sload(float v) {   // pin uniform to SGPR
    return __uint_as_float(__builtin_amdgcn_readfirstlane(__float_as_uint(v)));
}

__device__ __forceinline__ float rlane(float v, int i) {  // wave broadcast
    return __uint_as_float(__builtin_amdgcn_readlane(__float_as_uint(v), i));
}

__global__ __launch_bounds__(256, 5)
void fused_kernel(const float* __restrict__ posp,
                  const float* __restrict__ ancp,
                  const void* __restrict__ pmp,
                  const void* __restrict__ amp,
                  const float* __restrict__ msp,
                  const float* __restrict__ xfp,
                  float* __restrict__ partials) {
    const int tid = threadIdx.x;
    const int wv = tid >> 6;             // wave 0..3 (independent)
    const int l = tid & 63;              // lane
    const int b = blockIdx.x * 2 + (wv >> 1);   // batch for this wave
    const int w = wv & 1;                // 0 = rows (loss1), 1 = cols (loss2)

    // ---- mask element-width detection (uniform, cached) ----
    unsigned mw0 = ((const unsigned*)pmp)[l];
    bool okw = (mw0 == 0u) || (mw0 == 1u) || (mw0 == 0x3F800000u);
    unsigned hh0 = mw0 & 0xFFFFu, hh1 = mw0 >> 16;
    bool okh = (hh0 == 0u || hh0 == 0x3F80u) && (hh1 == 0u || hh1 == 0x3F80u);
    int mmode = (__ballot(okw) == ~0ULL) ? 0 : ((__ballot(okh) == ~0ULL) ? 1 : 2);

    // ---- transform, pinned to SGPRs ----
    float T[12];
#pragma unroll
    for (int e = 0; e < 3; ++e)
#pragma unroll
        for (int d = 0; d < 4; ++d) T[e * 4 + d] = sload(xfp[e * 4 + d]);

    // ---- own points: lane l = point l of batch b ----
    const int pb = (b * 64 + l) * 3;
    const float px = posp[pb], py = posp[pb + 1], pz = posp[pb + 2];
    const float r0 = ancp[pb], r1 = ancp[pb + 1], r2 = ancp[pb + 2];
    const float ax = T[0] * r0 + T[1] * r1 + T[2]  * r2 + T[3];
    const float ay = T[4] * r0 + T[5] * r1 + T[6]  * r2 + T[7];
    const float az = T[8] * r0 + T[9] * r1 + T[10] * r2 + T[11];

    // ---- masks -> per-wave ballots (SGPR pairs) ----
    const int mi = b * 64 + l;
    const unsigned long long pmM = __ballot(maskbit(pmp, mi, mmode) != 0);
    const unsigned long long amM = __ballot(maskbit(amp, mi, mmode) != 0);

    float psum = 0.f; int pcnt = 0; float slack;
    hf2 hc[32];                          // packed hinge candidates (32 VGPR)

    if (w == 0) {
        // ===== loss1: lane l = row l; 65 contiguous floats, lane-local ====
        const float* rowp = msp + (size_t)b * 4225 + l * 65;
        f4v ch[16];
#pragma unroll
        for (int c = 0; c < 16; ++c)
            __builtin_memcpy(&ch[c], rowp + 4 * c, 16);   // global_load_dwordx4
        slack = rowp[64];
        // ---- pin + fence: loads may NOT sink below this point ----
#pragma unroll
        for (int c = 0; c < 16; ++c) asm volatile("" : "+v"(ch[c]));
        asm volatile("" : "+v"(slack));
        asm volatile("" ::: "memory");

        const bool pmL = (pmM >> l) & 1ULL;
#pragma unroll
        for (int jj = 0; jj < 32; ++jj) {
            float h0, h1;
#pragma unroll
            for (int s = 0; s < 2; ++s) {
                const int j = 2 * jj + s;
                float v = ch[j >> 2][j & 3];           // register
                float bx = rlane(ax, j);               // anchor j broadcast
                float by = rlane(ay, j);
                float bz = rlane(az, j);
                float dx = px - bx, dy = py - by, dz = pz - bz;
                float d2 = dx * dx + dy * dy + dz * dz;
                bool pos = pmL && ((amM >> j) & 1ULL) && (d2 < R2_POS);
                psum -= pos ? v : 0.f;
                pcnt += pos ? 1 : 0;
                float hcv = (d2 > R2_NEG) ? v : HCNEG; // gt_neg UNMASKED
                if (s == 0) h0 = hcv; else h1 = hcv;
            }
            hf2 h; h[0] = (_Float16)h0; h[1] = (_Float16)h1;
            hc[jj] = h;
        }
    } else {
        // ===== loss2: lane l = col l; 64 coalesced dwords + slack, pinned =
        const float* mcol = msp + (size_t)b * 4225 + l;
        float vcol[64];
#pragma unroll
        for (int r = 0; r < 64; ++r) vcol[r] = mcol[r * 65];
        slack = mcol[64 * 65];
        // ---- pin + fence: loads may NOT sink below this point ----
#pragma unroll
        for (int r = 0; r < 64; ++r) asm volatile("" : "+v"(vcol[r]));
        asm volatile("" : "+v"(slack));
        asm volatile("" ::: "memory");

        const bool amL = (amM >> l) & 1ULL;
#pragma unroll
        for (int jj = 0; jj < 32; ++jj) {
            float h0, h1;
#pragma unroll
            for (int s = 0; s < 2; ++s) {
                const int r = 2 * jj + s;
                float v = vcol[r];                     // register
                float qx = rlane(px, r);               // point r broadcast
                float qy = rlane(py, r);
                float qz = rlane(pz, r);
                float dx = qx - ax, dy = qy - ay, dz = qz - az;
                float d2 = dx * dx + dy * dy + dz * dz;
                bool pos = ((pmM >> r) & 1ULL) && amL && (d2 < R2_POS);
                psum -= pos ? v : 0.f;
                pcnt += pos ? 1 : 0;
                float hcv = (d2 > R2_NEG) ? v : HCNEG;
                if (s == 0) h0 = hcv; else h1 = hcv;
            }
            hf2 h; h[0] = (_Float16)h0; h[1] = (_Float16)h1;
            hc[jj] = h;
        }
    }

    const float ps = pcnt ? psum / (float)pcnt : -slack;

    // ---- packed branch-free hinge: max(hc + (ps+gamma), 0), f32 accum ----
    const _Float16 ch16 = (_Float16)(ps + GAMMA_C);
    const hf2 C2 = {ch16, ch16};
    const hf2 Z = {(_Float16)0.f, (_Float16)0.f};
    float hv = 0.f;
#if __has_builtin(__builtin_amdgcn_fdot2)
    const hf2 ONE2 = {(_Float16)1.f, (_Float16)1.f};
#pragma unroll
    for (int k = 0; k < 32; ++k) {
        hf2 x = hc[k] + C2;                  // v_pk_add_f16
        x = __builtin_elementwise_max(x, Z); // v_pk_max_f16
        hv = __builtin_amdgcn_fdot2(x, ONE2, hv, false); // v_dot2_f32_f16
    }
#else
#pragma unroll
    for (int k = 0; k < 32; ++k) {
        hf2 x = hc[k] + C2;                  // v_pk_add_f16
        x = __builtin_elementwise_max(x, Z); // v_pk_max_f16
        hv += (float)x[0] + (float)x[1];
    }
#endif
    if (pcnt) hv += fmaxf(ps + slack + GAMMA_C, 0.f);
    float result = __logf(hv + 1.f);

    // ---- one butterfly per wave, lane0 stores partial ----
#pragma unroll
    for (int off = 1; off < 64; off <<= 1)
        result += __shfl_xor(result, off, 64);
    if (l == 0) partials[b * 2 + w] = result;          // plain store, no init
}

// Separate unconditional finalize (proven shape). float4 reads, 512 thr,
// 8-wave LDS reduce. Barrier OK here (off the fused value path).
// 4-byte dual-encoded write: low u16 = exact bf16 bits.
__global__ __launch_bounds__(512)
void finalize_kernel(const float* __restrict__ partials,
                     unsigned* __restrict__ out) {
    __shared__ float red[8];
    const int tid = threadIdx.x;
    float s = 0.f;
    // NPART floats = NPART/4 float4s; 512 threads -> 4 float4 each.
    const f4v* p4 = (const f4v*)partials;
#pragma unroll
    for (int k = 0; k < NPART / 4 / 512; ++k) {
        f4v v = p4[tid + 512 * k];
        s += v[0] + v[1] + v[2] + v[3];
    }
#pragma unroll
    for (int off = 1; off < 64; off <<= 1) s += __shfl_xor(s, off, 64);
    if ((tid & 63) == 0) red[tid >> 6] = s;
    __syncthreads();
    if (tid == 0) {
        float tot = 0.f;
#pragma unroll
        for (int i = 0; i < 8; ++i) tot += red[i];
        float loss = tot * (1.0f / (2.0f * NBATCH * 64.0f));
        unsigned bits = __float_as_uint(loss);
        unsigned h = (bits + 0x7FFFu + ((bits >> 16) & 1u)) >> 16;  // rne bf16
        out[0] = (h << 16) | h;
    }
}

extern "C" void kernel_launch(void* const* d_in, const int* in_sizes, int n_in,
                              void* d_out, int out_size, void* d_ws, size_t ws_size,
                              hipStream_t stream) {
    (void)in_sizes; (void)n_in; (void)out_size; (void)ws_size;
    const float* posp = (const float*)d_in[0];
    const float* ancp = (const float*)d_in[1];
    const void* pmp = d_in[2];
    const void* amp = d_in[3];
    const float* msp = (const float*)d_in[4];
    const float* xfp = (const float*)d_in[5];

    // ws[0..NPART): per-wave partials, fully overwritten every call.
    // 2048 blocks x 4 independent waves.
    fused_kernel<<<NBATCH / 2, 256, 0, stream>>>(posp, ancp, pmp, amp, msp,
                                                 xfp, (float*)d_ws);
    finalize_kernel<<<1, 512, 0, stream>>>((const float*)d_ws,
                                           (unsigned*)d_out);
}